// Round 1
// baseline (518.212 us; speedup 1.0000x reference)
//
#include <hip/hip_runtime.h>

#define HID   15
#define TMAIN 1024
#define FUT   64
#define OUTW  (TMAIN + FUT)   // 1088

typedef _Float16 v2h __attribute__((ext_vector_type(2)));

__device__ __forceinline__ float rcp_(float x)  { return __builtin_amdgcn_rcpf(x); }
__device__ __forceinline__ float exp2_(float x) { return __builtin_amdgcn_exp2f(x); }
__device__ __forceinline__ float tanh_(float x) {
    return __builtin_fmaf(2.0f, rcp_(1.0f + exp2_(x * -2.885390081777927f)), -1.0f);
}

template<int I> struct ic { static constexpr int v = I; };
template<int J, int N, class F>
__device__ __forceinline__ void unroll_for(F&& f) {
    if constexpr (J < N) { f(ic<J>{}); unroll_for<J + 1, N>(f); }
}

// DPP ctrl: 0x150+j = row_newbcast:j (CDNA), 0x110+n = row_shr:n, 0x101 = shl1
template<int CTRL>
__device__ __forceinline__ int dppi(int x) {
    return __builtin_amdgcn_update_dpp(0, x, CTRL, 0xF, 0xF, true);
}
template<int CTRL>
__device__ __forceinline__ float dppf(float x) {
    return __int_as_float(dppi<CTRL>(__float_as_int(x)));
}
__device__ __forceinline__ float row_sum_bcast(float p) {
    p += dppf<0x111>(p);
    p += dppf<0x112>(p);
    p += dppf<0x114>(p);
    p += dppf<0x118>(p);
    return dppf<0x15F>(p);
}
__device__ __forceinline__ float fdot2(v2h a, v2h b, float c) {
    return __builtin_amdgcn_fdot2(a, b, c, false);
}
// cvt_pkrtz returns __fp16x2; bit-cast to our v2h (same bits)
__device__ __forceinline__ v2h pkrtz(float lo, float hi) {
    return __builtin_bit_cast(v2h, __builtin_amdgcn_cvt_pkrtz(lo, hi));
}
// packed fp16 fma -> v_pk_fma_f16 (FULL-rate, vs v_dot2_f32_f16 half-rate)
__device__ __forceinline__ v2h pkfma(v2h a, v2h b, v2h c) {
    return __builtin_elementwise_fma(a, b, c);
}

// R10 = R9 with the dot engine swapped: v_dot2_f32_f16 (half-rate, 4cyc) ->
// v_pk_fma_f16 (full-rate, 2cyc) accumulating each gate in a packed fp16
// pair.  Each gate finishes with ONE fdot2 against {s,s} (s = m*sA[g]) with
// the exact f32 bias as c-operand: applies scale + horizontal add + bias in
// 4 cyc.  Weights now stored UNSCALED (|w|<=0.26) so fp16 accumulation
// magnitudes stay ~3x smaller; L2's 16-term dot splits into two 8-deep
// chains (w2h / w2i) merged by one v_pk_add_f16.  Pad lane k=15: s=0 kills
// the gate args -> sigmoid(0)=0.5, tanh(0)=0 -> h stays exactly 0.
// Model: 96 dots 384cyc -> 96 pkfma 192 + 8 fdot2 32 + 4 pkadd 8; step
// ~662 -> ~502 busy cyc.
__global__ __launch_bounds__(256)
__attribute__((amdgpu_waves_per_eu(1, 1)))
void lstm_seq_kernel(const float* __restrict__ input,
                     const float* __restrict__ W_ih1, const float* __restrict__ W_hh1,
                     const float* __restrict__ b_ih1, const float* __restrict__ b_hh1,
                     const float* __restrict__ W_ih2, const float* __restrict__ W_hh2,
                     const float* __restrict__ b_ih2, const float* __restrict__ b_hh2,
                     const float* __restrict__ W_lin, const float* __restrict__ b_lin,
                     float* __restrict__ out)
{
    const int tid  = threadIdx.x;
    const int wq   = tid >> 6;
    const int lane = tid & 63;
    const int g    = lane >> 4;       // batch subgroup == DPP row
    const int k    = lane & 15;       // hidden unit / time-slot (15 = pad unit)
    const int b0   = (blockIdx.x * 4 + wq) * 4;

    const bool pad = (k >= HID);
    const float m  = pad ? 0.0f : 1.0f;
    const int  kk  = pad ? 0 : k;

    const float L2E = 1.442695040888963f;
    const float sA[4] = {-L2E, -L2E, -2.0f * L2E, -L2E};

    const v2h z2 = (v2h){(_Float16)0.0f, (_Float16)0.0f};

    // UNSCALED packed fp16 weight pairs; pair 7 of w1 carries the x weight in .y
    v2h w1[4][8], w2i[4][8], w2h[4][8];
    v2h sp[4];                         // per-gate {s,s} finishing pair
    float bb1[4], bb2[4];
    #pragma unroll
    for (int gi = 0; gi < 4; ++gi) {
        const int row = gi * HID + kk;
        const float s = m * sA[gi];
        sp[gi]  = (v2h){(_Float16)s, (_Float16)s};
        bb1[gi] = s * (b_ih1[row] + b_hh1[row]);
        bb2[gi] = s * (b_ih2[row] + b_hh2[row]);
        #pragma unroll
        for (int j = 0; j < 8; ++j) {
            const int c0 = 2 * j, c1i = 2 * j + 1;
            w1 [gi][j] = (v2h){(_Float16)W_hh1[row * HID + c0],
                               (_Float16)((c1i < HID) ? W_hh1[row * HID + c1i]
                                                      : W_ih1[row])};   // x slot
            w2i[gi][j] = (v2h){(_Float16)W_ih2[row * HID + c0],
                               (_Float16)((c1i < HID) ? W_ih2[row * HID + c1i] : 0.0f)};
            w2h[gi][j] = (v2h){(_Float16)W_hh2[row * HID + c0],
                               (_Float16)((c1i < HID) ? W_hh2[row * HID + c1i] : 0.0f)};
        }
    }
    const float wl   = m * W_lin[kk];
    const float blin = b_lin[0];

    // lane k -> packed pair {h16[k], h16[k+1]} (lane15 edge -> 0 via bound_ctrl)
    auto packh = [&](float h) -> int {
        const _Float16 hh = (_Float16)h;                   // RNE
        const int lo = (int)(unsigned short)__builtin_bit_cast(unsigned short, hh);
        const int hi = dppi<0x101>(lo);
        const v2h pr = {__builtin_bit_cast(_Float16, (unsigned short)lo),
                        __builtin_bit_cast(_Float16, (unsigned short)(hi & 0xFFFF))};
        return __builtin_bit_cast(int, pr);
    };

    v2h hb1[8];                        // h1 broadcast pairs (persist across steps)
    #pragma unroll
    for (int j = 0; j < 8; ++j) hb1[j] = z2;
    int hpk2 = 0;                      // packed h2 = {0,0}
    float c1 = 0.0f, c2 = 0.0f;

    // one step. S = slot in 16-chunk (compile-time); USE_OV: xv for the next
    // step's pair-7 fix comes from ov (future / last main step) else xvpre.
    auto step = [&](auto Sc, auto UseOvC, float xvpre, float& oreg) {
        constexpr int  S      = decltype(Sc)::v;
        constexpr bool USE_OV = decltype(UseOvC)::v;

        // ---- layer-1 packed-fp16 dot chains (pair7.y carries x(t)) ----
        v2h a0 = z2, a1 = z2, a2 = z2, a3 = z2;
        unroll_for<0, 8>([&](auto jc) {
            constexpr int j = decltype(jc)::v;
            a0 = pkfma(w1[0][j], hb1[j], a0);
            a1 = pkfma(w1[1][j], hb1[j], a1);
            a2 = pkfma(w1[2][j], hb1[j], a2);
            a3 = pkfma(w1[3][j], hb1[j], a3);
        });

        // ---- layer-2 hh chains (prev h2; fills L1-act latency) ----
        v2h e0 = z2, e1 = z2, e2 = z2, e3 = z2;
        unroll_for<0, 8>([&](auto jc) {
            constexpr int j = decltype(jc)::v;
            const v2h hb = __builtin_bit_cast(v2h, dppi<0x150 + 2*j>(hpk2));
            e0 = pkfma(w2h[0][j], hb, e0);
            e1 = pkfma(w2h[1][j], hb, e1);
            e2 = pkfma(w2h[2][j], hb, e2);
            e3 = pkfma(w2h[3][j], hb, e3);
        });

        // ---- layer-1 finish (scale + hadd + bias in one fdot2), acts ----
        const float A0 = fdot2(sp[0], a0, bb1[0]);
        const float A1 = fdot2(sp[1], a1, bb1[1]);
        const float A2 = fdot2(sp[2], a2, bb1[2]);
        const float A3 = fdot2(sp[3], a3, bb1[3]);
        const float ig = rcp_(1.0f + exp2_(A0));
        const float fg = rcp_(1.0f + exp2_(A1));
        const float gg = __builtin_fmaf(2.0f, rcp_(1.0f + exp2_(A2)), -1.0f);
        const float og = rcp_(1.0f + exp2_(A3));
        c1 = __builtin_fmaf(fg, c1, ig * gg);
        const float h1n = og * tanh_(c1);

        // ---- build hb1 once (L2-ih now; L1-hh next step) ----
        const int hpk1 = packh(h1n);
        unroll_for<0, 8>([&](auto jc) {
            constexpr int j = decltype(jc)::v;
            hb1[j] = __builtin_bit_cast(v2h, dppi<0x150 + 2*j>(hpk1));
        });

        // ---- layer-2 ih chains ----
        v2h f0 = z2, f1 = z2, f2 = z2, f3 = z2;
        unroll_for<0, 8>([&](auto jc) {
            constexpr int j = decltype(jc)::v;
            f0 = pkfma(w2i[0][j], hb1[j], f0);
            f1 = pkfma(w2i[1][j], hb1[j], f1);
            f2 = pkfma(w2i[2][j], hb1[j], f2);
            f3 = pkfma(w2i[3][j], hb1[j], f3);
        });

        // ---- merge the two 8-deep chains, finish, layer-2 acts ----
        const v2h d0 = e0 + f0;
        const v2h d1 = e1 + f1;
        const v2h d2 = e2 + f2;
        const v2h d3 = e3 + f3;
        const float D0 = fdot2(sp[0], d0, bb2[0]);
        const float D1 = fdot2(sp[1], d1, bb2[1]);
        const float D2 = fdot2(sp[2], d2, bb2[2]);
        const float D3 = fdot2(sp[3], d3, bb2[3]);
        const float i2 = rcp_(1.0f + exp2_(D0));
        const float f2g = rcp_(1.0f + exp2_(D1));
        const float g2 = __builtin_fmaf(2.0f, rcp_(1.0f + exp2_(D2)), -1.0f);
        const float o2 = rcp_(1.0f + exp2_(D3));
        c2 = __builtin_fmaf(f2g, c2, i2 * g2);
        const float h2n = o2 * tanh_(c2);
        hpk2 = packh(h2n);

        // ---- out = <W_lin, h2> + b; keep own slot ----
        const float ov = row_sum_bcast(wl * h2n) + blin;
        oreg = (k == S) ? ov : oreg;

        // ---- pair-7 fix: {h1[14], x(t+1)} for the next step's L1 ----
        const float xv = USE_OV ? ov : xvpre;
        hb1[7] = pkrtz(dppf<0x15E>(h1n), xv);
    };

    const size_t inb  = (size_t)(b0 + g) * TMAIN + k;
    const size_t outb = (size_t)(b0 + g) * OUTW  + k;

    float xcur = input[inb];
    // prologue: x(0) into pair7.y
    hb1[7] = pkrtz(0.0f, dppf<0x150>(xcur));

    // ---- main: 64 chunks of 16 steps; x prefetched one chunk ahead ----
    #pragma unroll 1
    for (int ch = 0; ch < TMAIN / 16; ++ch) {
        const bool last = (ch == TMAIN / 16 - 1);
        const float xnext = input[inb + (last ? ch : ch + 1) * 16];
        float oreg = 0.0f;
        unroll_for<0, 16>([&](auto sc) {
            constexpr int s = decltype(sc)::v;
            if constexpr (s < 15) {
                step(sc, ic<0>{}, dppf<0x150 + s + 1>(xcur), oreg);
            } else {
                // s==15: next x comes from the next chunk (or ov on last chunk)
                if (last) step(sc, ic<1>{}, 0.0f, oreg);
                else      step(sc, ic<0>{}, dppf<0x150>(xnext), oreg);
            }
        });
        out[outb + ch * 16] = oreg;
        xcur = xnext;
    }

    // ---- future: x = previous out (handled by USE_OV pair-7 fix) ----
    #pragma unroll 1
    for (int ch = 0; ch < FUT / 16; ++ch) {
        float oreg = 0.0f;
        unroll_for<0, 16>([&](auto sc) {
            step(sc, ic<1>{}, 0.0f, oreg);
        });
        out[outb + TMAIN + ch * 16] = oreg;
    }
}

extern "C" void kernel_launch(void* const* d_in, const int* in_sizes, int n_in,
                              void* d_out, int out_size, void* d_ws, size_t ws_size,
                              hipStream_t stream)
{
    const float* input = (const float*)d_in[0];
    const float* W_ih1 = (const float*)d_in[1];
    const float* W_hh1 = (const float*)d_in[2];
    const float* b_ih1 = (const float*)d_in[3];
    const float* b_hh1 = (const float*)d_in[4];
    const float* W_ih2 = (const float*)d_in[5];
    const float* W_hh2 = (const float*)d_in[6];
    const float* b_ih2 = (const float*)d_in[7];
    const float* b_hh2 = (const float*)d_in[8];
    const float* W_lin = (const float*)d_in[9];
    const float* b_lin = (const float*)d_in[10];
    // d_in[11] = future (=64), compiled in as FUT

    // 4096 batches / (4 per wave * 4 waves per block) = 256 blocks
    lstm_seq_kernel<<<256, 256, 0, stream>>>(
        input, W_ih1, W_hh1, b_ih1, b_hh1,
        W_ih2, W_hh2, b_ih2, b_hh2, W_lin, b_lin,
        (float*)d_out);
}